// Round 7
// baseline (1708.844 us; speedup 1.0000x reference)
//
#include <hip/hip_runtime.h>
#include <stdint.h>

#define NB 4
#define NC 256
#define NCI 128
#define NN 4096

// ---------------------------------------------------------------- sentinel fill
__global__ void k_fill(float* __restrict__ p, float v, int n) {
    int i = blockIdx.x * blockDim.x + threadIdx.x;
    if (i < n) p[i] = v;
}

// ---------------------------------------------------------------- K1: naive QKV (f32)
// theta[b][ci][n] = sum_c Wt[ci][c] x[b][c][n] + bt[ci]; ditto phi, g.
// Stores: theta/phi as [b][n][ci] f32; g as [b][ci][n] f32.
__global__ __launch_bounds__(256) void k_qkv_naive(
    const float* __restrict__ x,
    const float* __restrict__ Wt, const float* __restrict__ bt,
    const float* __restrict__ Wp, const float* __restrict__ bp,
    const float* __restrict__ Wg, const float* __restrict__ bg,
    float* __restrict__ thetaT, float* __restrict__ phiT,
    float* __restrict__ gout) {
    const int b = blockIdx.z;
    const int ci = blockIdx.y * 8 + (threadIdx.x >> 5);
    const int nb = blockIdx.x * 512 + (threadIdx.x & 31);

    float at[16], ap[16], ag[16];
#pragma unroll
    for (int k = 0; k < 16; k++) { at[k] = 0.f; ap[k] = 0.f; ag[k] = 0.f; }

    const float* wtr = Wt + (size_t)ci * NC;
    const float* wpr = Wp + (size_t)ci * NC;
    const float* wgr = Wg + (size_t)ci * NC;

    for (int c = 0; c < NC; c++) {
        float wt = wtr[c], wp = wpr[c], wg = wgr[c];
        const float* xr = x + ((size_t)(b * NC + c)) * NN + nb;
#pragma unroll
        for (int k = 0; k < 16; k++) {
            float xv = xr[32 * k];
            at[k] = fmaf(wt, xv, at[k]);
            ap[k] = fmaf(wp, xv, ap[k]);
            ag[k] = fmaf(wg, xv, ag[k]);
        }
    }
    float bt_v = bt[ci], bp_v = bp[ci], bg_v = bg[ci];
#pragma unroll
    for (int k = 0; k < 16; k++) {
        int n = nb + 32 * k;
        thetaT[((size_t)(b * NN + n)) * NCI + ci] = at[k] + bt_v;
        phiT[((size_t)(b * NN + n)) * NCI + ci]   = ap[k] + bp_v;
        gout[((size_t)(b * NCI + ci)) * NN + n]   = ag[k] + bg_v;
    }
}

// ---------------------------------------------------------------- K2: naive attention (f32)
// Block: batch b, 64 queries. Softmax without max-subtraction is exact here:
// logits sigma~11, max ~< 70 < 88 (f32 exp overflow).
__global__ __launch_bounds__(256) void k_attn_naive(
    const float* __restrict__ thetaT, const float* __restrict__ phiT,
    const float* __restrict__ gmat, float* __restrict__ OTc) {
    constexpr int TH_LD = 132, PH_LD = 132, EL_LD = 68;
    __shared__ float sTh[64 * TH_LD];    // theta [q][ci]
    __shared__ float sPh[128 * PH_LD];   // phi tile [m][ci]
    __shared__ float sEl[128 * EL_LD];   // E tile [m][q]
    __shared__ float sSum[256];
    __shared__ float sInv[64];
    const int b = blockIdx.y, n0 = blockIdx.x * 64;
    const int tid = threadIdx.x;

    // stage theta (64 q x 128 ci)
#pragma unroll
    for (int i = 0; i < 8; i++) {
        int qq = tid + i * 256;                 // 2048 float4 groups
        int row = qq >> 5, seg = qq & 31;
        *(float4*)&sTh[row * TH_LD + seg * 4] =
            *(const float4*)&thetaT[((size_t)(b * NN + n0 + row)) * NCI + seg * 4];
    }

    const int qa = tid >> 2, sa = tid & 3;    // phase A: query, key-subset
    const int cb = tid & 127, hb = tid >> 7;  // phase B: channel, query-half
    float sacc = 0.f;
    float Oacc[32];
#pragma unroll
    for (int i = 0; i < 32; i++) Oacc[i] = 0.f;

    for (int m0 = 0; m0 < NN; m0 += 128) {
        __syncthreads();  // phase B(prev) done with sEl; covers sTh staging on first iter
        // stage phi tile (128 m x 128 ci)
#pragma unroll
        for (int i = 0; i < 16; i++) {
            int qq = tid + i * 256;             // 4096 float4 groups
            int row = qq >> 5, seg = qq & 31;
            *(float4*)&sPh[row * PH_LD + seg * 4] =
                *(const float4*)&phiT[((size_t)(b * NN + m0 + row)) * NCI + seg * 4];
        }
        __syncthreads();
        // phase A: logits + exp; thread (qa, sa) handles keys sa+4k
        for (int k = 0; k < 32; k++) {
            int mloc = sa + 4 * k;
            const float* th = &sTh[qa * TH_LD];
            const float* ph = &sPh[mloc * PH_LD];
            float dot = 0.f;
#pragma unroll
            for (int c = 0; c < 128; c += 4) {
                float4 t4 = *(const float4*)&th[c];
                float4 p4 = *(const float4*)&ph[c];
                dot = fmaf(t4.x, p4.x, dot); dot = fmaf(t4.y, p4.y, dot);
                dot = fmaf(t4.z, p4.z, dot); dot = fmaf(t4.w, p4.w, dot);
            }
            float e = __expf(dot);
            sEl[mloc * EL_LD + qa] = e;
            sacc += e;
        }
        __syncthreads();
        // phase B: O[cb][q] += sum_m E[m][q] * g[cb][m]
        const float* gr = &gmat[((size_t)(b * NCI + cb)) * NN + m0];
        for (int m4 = 0; m4 < 32; m4++) {
            float4 gv = *(const float4*)&gr[m4 * 4];
#pragma unroll
            for (int j = 0; j < 4; j++) {
                float gval = (j == 0) ? gv.x : (j == 1) ? gv.y : (j == 2) ? gv.z : gv.w;
                const float* el = &sEl[(m4 * 4 + j) * EL_LD + hb * 32];
#pragma unroll
                for (int q4 = 0; q4 < 8; q4++) {
                    float4 e4 = *(const float4*)&el[q4 * 4];
                    Oacc[q4 * 4 + 0] = fmaf(e4.x, gval, Oacc[q4 * 4 + 0]);
                    Oacc[q4 * 4 + 1] = fmaf(e4.y, gval, Oacc[q4 * 4 + 1]);
                    Oacc[q4 * 4 + 2] = fmaf(e4.z, gval, Oacc[q4 * 4 + 2]);
                    Oacc[q4 * 4 + 3] = fmaf(e4.w, gval, Oacc[q4 * 4 + 3]);
                }
            }
        }
    }
    // combine per-thread partial sums (4 per query)
    sSum[tid] = sacc;
    __syncthreads();
    if (tid < 64) {
        float s = sSum[tid * 4] + sSum[tid * 4 + 1] + sSum[tid * 4 + 2] + sSum[tid * 4 + 3];
        sInv[tid] = 1.0f / s;
    }
    __syncthreads();
#pragma unroll
    for (int q4 = 0; q4 < 32; q4++) {
        int q = hb * 32 + q4;
        OTc[((size_t)(b * NCI + cb)) * NN + n0 + q] = Oacc[q4] * sInv[q];
    }
}

// ---------------------------------------------------------------- K3: naive out proj + residual (f32)
// y[b][o][n] = sum_ci Wo[o][ci] * OTc[b][ci][n] + bo[o] + x[b][o][n]
__global__ __launch_bounds__(256) void k_out_naive(
    const float* __restrict__ OTc, const float* __restrict__ Wo,
    const float* __restrict__ bo, const float* __restrict__ x,
    float* __restrict__ y) {
    const int b = blockIdx.z;
    const int o = blockIdx.y * 8 + (threadIdx.x >> 5);
    const int nb = blockIdx.x * 512 + (threadIdx.x & 31);

    float acc[16];
#pragma unroll
    for (int k = 0; k < 16; k++) acc[k] = 0.f;
    const float* wr = Wo + (size_t)o * NCI;

    for (int ci = 0; ci < NCI; ci++) {
        float w = wr[ci];
        const float* otr = OTc + ((size_t)(b * NCI + ci)) * NN + nb;
#pragma unroll
        for (int k = 0; k < 16; k++)
            acc[k] = fmaf(w, otr[32 * k], acc[k]);
    }
    float bias = bo[o];
#pragma unroll
    for (int k = 0; k < 16; k++) {
        size_t idx = ((size_t)(b * NC + o)) * NN + nb + 32 * k;
        y[idx] = acc[k] + bias + x[idx];
    }
}

// ---------------------------------------------------------------- launch
// f32 everywhere. d_out (f32, 16 MB) doubles as theta/phi scratch until k_out
// overwrites it with y. ws: g (8 MB) + OTc (8 MB) = 16 MB.
// Runtime gates emit distinguishable sentinels if contract assumptions fail:
//   absmax ~777 -> in_sizes/shape mismatch; ~555 -> ws_size < 16 MB.
extern "C" void kernel_launch(void* const* d_in, const int* in_sizes, int n_in,
                              void* d_out, int out_size, void* d_ws, size_t ws_size,
                              hipStream_t stream) {
    float* y = (float*)d_out;

    bool sizes_ok = (n_in == 9) &&
        in_sizes[0] == NB * NC * NN &&      // x
        in_sizes[1] == NCI * NC &&          // theta_w
        in_sizes[2] == NCI &&               // theta_b
        in_sizes[3] == NCI * NC &&          // phi_w
        in_sizes[4] == NCI &&               // phi_b
        in_sizes[5] == NCI * NC &&          // g_w
        in_sizes[6] == NCI &&               // g_b
        in_sizes[7] == NC * NCI &&          // out_w
        in_sizes[8] == NC &&                // out_b
        out_size == NB * NC * NN;
    if (!sizes_ok) {
        k_fill<<<(out_size + 255) / 256, 256, 0, stream>>>(y, 777.0f, out_size);
        return;
    }
    if (ws_size < (size_t)16 * 1024 * 1024) {
        k_fill<<<(out_size + 255) / 256, 256, 0, stream>>>(y, 555.0f, out_size);
        return;
    }

    const float* x  = (const float*)d_in[0];
    const float* tw = (const float*)d_in[1];
    const float* tb = (const float*)d_in[2];
    const float* pw = (const float*)d_in[3];
    const float* pb = (const float*)d_in[4];
    const float* gw = (const float*)d_in[5];
    const float* gb = (const float*)d_in[6];
    const float* ow = (const float*)d_in[7];
    const float* obias = (const float*)d_in[8];

    float* thetaT = (float*)d_out;               // [B][N][Ci] f32, 8 MB (scratch)
    float* phiT   = (float*)d_out + 2097152;     // [B][N][Ci] f32, 8 MB (scratch)
    float* g      = (float*)d_ws;                // [B][Ci][N] f32, 8 MB
    float* OTc    = (float*)d_ws + 2097152;      // [B][Ci][N] f32, 8 MB

    k_qkv_naive<<<dim3(NN / 512, NCI / 8, NB), 256, 0, stream>>>(
        x, tw, tb, pw, pb, gw, gb, thetaT, phiT, g);
    k_attn_naive<<<dim3(NN / 64, NB), 256, 0, stream>>>(thetaT, phiT, g, OTc);
    k_out_naive<<<dim3(NN / 512, NC / 8, NB), 256, 0, stream>>>(OTc, ow, obias, x, y);
}

// Round 8
// 290.158 us; speedup vs baseline: 5.8893x; 5.8893x over previous
//
#include <hip/hip_runtime.h>
#include <stdint.h>

#define NB 4
#define NC 256
#define NCI 128
#define NN 4096

typedef __attribute__((ext_vector_type(8))) short short8;
typedef __attribute__((ext_vector_type(4))) float f32x4;

__device__ __forceinline__ float bf2f(unsigned short u) {
    union { unsigned int i; float f; } v; v.i = ((unsigned int)u) << 16; return v.f;
}
__device__ __forceinline__ unsigned short f2bf(float f) {
    union { unsigned int i; float f; } v; v.f = f;
    unsigned int b = v.i;
    b += 0x7FFFu + ((b >> 16) & 1u);   // RNE
    return (unsigned short)(b >> 16);
}

// ---------------------------------------------------------------- sentinel fill
__global__ void k_fill(float* __restrict__ p, float v, int n) {
    int i = blockIdx.x * blockDim.x + threadIdx.x;
    if (i < n) p[i] = v;
}

// ---------------------------------------------------------------- K1: phi (hi/lo split) + g projections
// phi = Wp·x + bp computed f32-grade: (Wh+Wl)(xh+xl) ~ Wh·xh + Wh·xl + Wl·xh.
// Stored as hi/lo bf16 pair [b][n][ci]. g = Wg·x + bg plain bf16 [b][ci][n].
__global__ __launch_bounds__(256, 1) void k_qkv2(
    const float* __restrict__ x,
    const float* __restrict__ Wp, const float* __restrict__ bp,
    const float* __restrict__ Wg, const float* __restrict__ bg,
    unsigned short* __restrict__ phiH, unsigned short* __restrict__ phiL,
    unsigned short* __restrict__ gout) {
    constexpr int LD = 40;
    __shared__ __align__(16) unsigned short sXh[128 * LD];
    __shared__ __align__(16) unsigned short sXl[128 * LD];
    __shared__ __align__(16) unsigned short sWh[128 * LD];
    __shared__ __align__(16) unsigned short sWl[128 * LD];
    __shared__ __align__(16) unsigned short sWg[128 * LD];
    const int b = blockIdx.y, n0 = blockIdx.x * 128;
    const int tid = threadIdx.x, lane = tid & 63, wave = tid >> 6;
    const int wm = (wave >> 1) * 64, wn = (wave & 1) * 64;
    const int col = lane & 15, quad = lane >> 4;

    f32x4 accP[4][4], accG[4][4];
#pragma unroll
    for (int i = 0; i < 4; i++)
#pragma unroll
        for (int j = 0; j < 4; j++)
#pragma unroll
            for (int e = 0; e < 4; e++) { accP[i][j][e] = 0.f; accG[i][j][e] = 0.f; }

    const int wrow = tid >> 1, whalf = tid & 1;

    for (int k0 = 0; k0 < NC; k0 += 32) {
        // W staging: rows [128 ci][32 c]; Wp split hi/lo, Wg hi only
        {
            const float* wp = Wp + (size_t)wrow * NC + k0 + whalf * 16;
            const float* wg = Wg + (size_t)wrow * NC + k0 + whalf * 16;
#pragma unroll
            for (int j = 0; j < 4; j++) {
                float4 v = *(const float4*)&wp[j * 4];
                unsigned short h0 = f2bf(v.x), h1 = f2bf(v.y), h2 = f2bf(v.z), h3 = f2bf(v.w);
                ushort4 hv = { h0, h1, h2, h3 };
                ushort4 lv = { f2bf(v.x - bf2f(h0)), f2bf(v.y - bf2f(h1)),
                               f2bf(v.z - bf2f(h2)), f2bf(v.w - bf2f(h3)) };
                *(ushort4*)&sWh[wrow * LD + whalf * 16 + j * 4] = hv;
                *(ushort4*)&sWl[wrow * LD + whalf * 16 + j * 4] = lv;
                float4 g4 = *(const float4*)&wg[j * 4];
                ushort4 gv = { f2bf(g4.x), f2bf(g4.y), f2bf(g4.z), f2bf(g4.w) };
                *(ushort4*)&sWg[wrow * LD + whalf * 16 + j * 4] = gv;
            }
        }
        // x transpose-stage: x[b][k0+cc][n0+nn] -> sX[nn][cc], split hi/lo
#pragma unroll
        for (int rr = 0; rr < 2; rr++) {
            int cc = rr * 16 + (tid >> 4);
            int nn = (tid & 15) * 8;
            const float* xp = x + ((size_t)(b * NC + k0 + cc)) * NN + n0 + nn;
#pragma unroll
            for (int j = 0; j < 8; j++) {
                float v = xp[j];
                unsigned short h = f2bf(v);
                sXh[(nn + j) * LD + cc] = h;
                sXl[(nn + j) * LD + cc] = f2bf(v - bf2f(h));
            }
        }
        __syncthreads();
        short8 awh[4], awl[4], ag[4], bxh[4], bxl[4];
#pragma unroll
        for (int i = 0; i < 4; i++) {
            awh[i] = *(const short8*)&sWh[(wm + i * 16 + col) * LD + quad * 8];
            awl[i] = *(const short8*)&sWl[(wm + i * 16 + col) * LD + quad * 8];
            ag[i]  = *(const short8*)&sWg[(wm + i * 16 + col) * LD + quad * 8];
        }
#pragma unroll
        for (int j = 0; j < 4; j++) {
            bxh[j] = *(const short8*)&sXh[(wn + j * 16 + col) * LD + quad * 8];
            bxl[j] = *(const short8*)&sXl[(wn + j * 16 + col) * LD + quad * 8];
        }
#pragma unroll
        for (int i = 0; i < 4; i++)
#pragma unroll
            for (int j = 0; j < 4; j++) {
                accP[i][j] = __builtin_amdgcn_mfma_f32_16x16x32_bf16(awh[i], bxh[j], accP[i][j], 0, 0, 0);
                accP[i][j] = __builtin_amdgcn_mfma_f32_16x16x32_bf16(awh[i], bxl[j], accP[i][j], 0, 0, 0);
                accP[i][j] = __builtin_amdgcn_mfma_f32_16x16x32_bf16(awl[i], bxh[j], accP[i][j], 0, 0, 0);
                accG[i][j] = __builtin_amdgcn_mfma_f32_16x16x32_bf16(ag[i],  bxh[j], accG[i][j], 0, 0, 0);
            }
        __syncthreads();
    }
#pragma unroll
    for (int i = 0; i < 4; i++) {
        int mrow = wm + i * 16 + quad * 4;
#pragma unroll
        for (int j = 0; j < 4; j++) {
            int n = n0 + wn + j * 16 + col;
            unsigned short h[4], l[4];
#pragma unroll
            for (int e = 0; e < 4; e++) {
                float v = accP[i][j][e] + bp[mrow + e];
                h[e] = f2bf(v);
                l[e] = f2bf(v - bf2f(h[e]));
            }
            uint2 hv, lv;
            hv.x = (unsigned int)h[0] | ((unsigned int)h[1] << 16);
            hv.y = (unsigned int)h[2] | ((unsigned int)h[3] << 16);
            lv.x = (unsigned int)l[0] | ((unsigned int)l[1] << 16);
            lv.y = (unsigned int)l[2] | ((unsigned int)l[3] << 16);
            *(uint2*)&phiH[((size_t)(b * NN + n)) * NCI + mrow] = hv;
            *(uint2*)&phiL[((size_t)(b * NN + n)) * NCI + mrow] = lv;
#pragma unroll
            for (int r = 0; r < 4; r++)
                gout[((size_t)(b * NCI + mrow + r)) * NN + n] = f2bf(accG[i][j][r] + bg[mrow + r]);
        }
    }
}

// ---------------------------------------------------------------- K2: fused attention
// Per block: batch b, 64 queries (XCD-swizzled). Prologue computes theta
// (f32-grade split conv) in-kernel; K-loop does split-QK + exp (no max-sub,
// logits < 88) + PV; epilogue fuses out-proj + bias + residual.
__global__ __launch_bounds__(256, 1) void k_attn(
    const float* __restrict__ x,
    const float* __restrict__ Wt, const float* __restrict__ bt,
    const unsigned short* __restrict__ phiH, const unsigned short* __restrict__ phiL,
    const unsigned short* __restrict__ gmat,
    const float* __restrict__ Wo, const float* __restrict__ bo,
    float* __restrict__ y) {
    __shared__ __align__(16) char smem[97280];
    unsigned short* sThH = (unsigned short*)(smem);            // [64 q][136]
    unsigned short* sThL = (unsigned short*)(smem + 17408);
    unsigned short* sWth = (unsigned short*)(smem + 34816);    // prologue [128 ci][72]
    unsigned short* sWtl = (unsigned short*)(smem + 53248);
    unsigned short* sXh  = (unsigned short*)(smem + 71680);    // prologue [64 n][72]
    unsigned short* sXl  = (unsigned short*)(smem + 80896);
    unsigned short* sPhiH = (unsigned short*)(smem + 34816);   // main [64 m][136]
    unsigned short* sPhiL = (unsigned short*)(smem + 52224);
    unsigned short* sG    = (unsigned short*)(smem + 69632);   // main [128 c][72]
    unsigned short* sPall = (unsigned short*)(smem + 88064);   // [4 waves][16 q][72]
    unsigned short* sO    = (unsigned short*)(smem);           // epilogue [64 q][136]
    unsigned short* sWo   = (unsigned short*)(smem + 17408);   // epilogue [64 o][136]

    const int id = blockIdx.x;
    const int xcd = id & 7, slot = id >> 3;
    const int b = xcd >> 1;
    const int n0 = (slot * 2 + (xcd & 1)) * 64;   // bijective (b, n-tile) cover

    const int tid = threadIdx.x, lane = tid & 63, wave = tid >> 6;
    const int col = lane & 15, quad = lane >> 4;
    unsigned short* sP = sPall + wave * 16 * 72;
    const int bsrc = (col >> 2) << 4, rsel = col & 3;

    // ---------------- prologue: theta[q 64][ci 128], f32-grade
    f32x4 th[2][4];
#pragma unroll
    for (int i = 0; i < 2; i++)
#pragma unroll
        for (int j = 0; j < 4; j++)
#pragma unroll
            for (int e = 0; e < 4; e++) th[i][j][e] = 0.f;
    const int wci = wave * 32;
    const int wrow = tid >> 1, whalf = tid & 1;

    for (int c0 = 0; c0 < NC; c0 += 64) {
        {   // Wt tile [128 ci][64 c] hi/lo
            const float* wp = Wt + (size_t)wrow * NC + c0 + whalf * 32;
#pragma unroll
            for (int j = 0; j < 8; j++) {
                float4 v = *(const float4*)&wp[j * 4];
                unsigned short h0 = f2bf(v.x), h1 = f2bf(v.y), h2 = f2bf(v.z), h3 = f2bf(v.w);
                ushort4 hv = { h0, h1, h2, h3 };
                ushort4 lv = { f2bf(v.x - bf2f(h0)), f2bf(v.y - bf2f(h1)),
                               f2bf(v.z - bf2f(h2)), f2bf(v.w - bf2f(h3)) };
                *(ushort4*)&sWth[wrow * 72 + whalf * 32 + j * 4] = hv;
                *(ushort4*)&sWtl[wrow * 72 + whalf * 32 + j * 4] = lv;
            }
        }
        // x tile [64 n][64 c] transpose-split
#pragma unroll
        for (int rr = 0; rr < 4; rr++) {
            int cc = rr * 16 + (tid >> 4);
            int nn = (tid & 15) * 4;
            const float* xp = x + ((size_t)(b * NC + c0 + cc)) * NN + n0 + nn;
            float4 v = *(const float4*)xp;
            float vv[4] = { v.x, v.y, v.z, v.w };
#pragma unroll
            for (int j = 0; j < 4; j++) {
                unsigned short h = f2bf(vv[j]);
                sXh[(nn + j) * 72 + cc] = h;
                sXl[(nn + j) * 72 + cc] = f2bf(vv[j] - bf2f(h));
            }
        }
        __syncthreads();
#pragma unroll
        for (int ks = 0; ks < 2; ks++) {
            short8 ah[2], al[2], bh[4], bl[4];
#pragma unroll
            for (int i = 0; i < 2; i++) {
                ah[i] = *(const short8*)&sWth[(wci + i * 16 + col) * 72 + ks * 32 + quad * 8];
                al[i] = *(const short8*)&sWtl[(wci + i * 16 + col) * 72 + ks * 32 + quad * 8];
            }
#pragma unroll
            for (int j = 0; j < 4; j++) {
                bh[j] = *(const short8*)&sXh[(j * 16 + col) * 72 + ks * 32 + quad * 8];
                bl[j] = *(const short8*)&sXl[(j * 16 + col) * 72 + ks * 32 + quad * 8];
            }
#pragma unroll
            for (int i = 0; i < 2; i++)
#pragma unroll
                for (int j = 0; j < 4; j++) {
                    th[i][j] = __builtin_amdgcn_mfma_f32_16x16x32_bf16(ah[i], bh[j], th[i][j], 0, 0, 0);
                    th[i][j] = __builtin_amdgcn_mfma_f32_16x16x32_bf16(ah[i], bl[j], th[i][j], 0, 0, 0);
                    th[i][j] = __builtin_amdgcn_mfma_f32_16x16x32_bf16(al[i], bh[j], th[i][j], 0, 0, 0);
                }
        }
        __syncthreads();
    }
    // bias + split -> sTh
#pragma unroll
    for (int i = 0; i < 2; i++) {
        int ci = wci + i * 16 + quad * 4;
#pragma unroll
        for (int j = 0; j < 4; j++) {
            int q = j * 16 + col;
            unsigned short h[4], l[4];
#pragma unroll
            for (int e = 0; e < 4; e++) {
                float v = th[i][j][e] + bt[ci + e];
                h[e] = f2bf(v);
                l[e] = f2bf(v - bf2f(h[e]));
            }
            uint2 hv, lv;
            hv.x = (unsigned int)h[0] | ((unsigned int)h[1] << 16);
            hv.y = (unsigned int)h[2] | ((unsigned int)h[3] << 16);
            lv.x = (unsigned int)l[0] | ((unsigned int)l[1] << 16);
            lv.y = (unsigned int)l[2] | ((unsigned int)l[3] << 16);
            *(uint2*)&sThH[q * 136 + ci] = hv;
            *(uint2*)&sThL[q * 136 + ci] = lv;
        }
    }
    __syncthreads();
    short8 qh[4], ql[4];
#pragma unroll
    for (int ks = 0; ks < 4; ks++) {
        qh[ks] = *(const short8*)&sThH[(wave * 16 + col) * 136 + ks * 32 + quad * 8];
        ql[ks] = *(const short8*)&sThL[(wave * 16 + col) * 136 + ks * 32 + quad * 8];
    }

    // ---------------- main K-loop
    f32x4 oacc[8];
#pragma unroll
    for (int i = 0; i < 8; i++)
#pragma unroll
        for (int e = 0; e < 4; e++) oacc[i][e] = 0.f;
    float li[4] = { 0.f, 0.f, 0.f, 0.f };

    for (int m0 = 0; m0 < NN; m0 += 64) {
        __syncthreads();   // prev PV done with sG/sP before restage
#pragma unroll
        for (int i = 0; i < 4; i++) {
            int q = tid + i * 256;
            int row = q >> 4, seg = q & 15;
            size_t src = ((size_t)(b * NN + m0 + row)) * NCI + seg * 8;
            *(uint4*)&sPhiH[row * 136 + seg * 8] = *(const uint4*)&phiH[src];
            *(uint4*)&sPhiL[row * 136 + seg * 8] = *(const uint4*)&phiL[src];
        }
#pragma unroll
        for (int i = 0; i < 4; i++) {
            int q = tid + i * 256;
            int row = q >> 3, seg = q & 7;
            *(uint4*)&sG[row * 72 + seg * 8] =
                *(const uint4*)&gmat[((size_t)(b * NCI + row)) * NN + m0 + seg * 8];
        }
        __syncthreads();

        f32x4 S[4];
#pragma unroll
        for (int mtl = 0; mtl < 4; mtl++) {
            f32x4 a;
#pragma unroll
            for (int e = 0; e < 4; e++) a[e] = 0.f;
#pragma unroll
            for (int ks = 0; ks < 4; ks++) {
                short8 ph = *(const short8*)&sPhiH[(mtl * 16 + col) * 136 + ks * 32 + quad * 8];
                short8 pl = *(const short8*)&sPhiL[(mtl * 16 + col) * 136 + ks * 32 + quad * 8];
                a = __builtin_amdgcn_mfma_f32_16x16x32_bf16(qh[ks], ph, a, 0, 0, 0);
                a = __builtin_amdgcn_mfma_f32_16x16x32_bf16(qh[ks], pl, a, 0, 0, 0);
                a = __builtin_amdgcn_mfma_f32_16x16x32_bf16(ql[ks], ph, a, 0, 0, 0);
            }
            S[mtl] = a;
        }
        // exp (no max-subtraction: logits < ~70), row-sum, stash P bf16
        float pv[4][4];
#pragma unroll
        for (int r = 0; r < 4; r++) {
            float rs = 0.f;
#pragma unroll
            for (int mtl = 0; mtl < 4; mtl++) {
                float p = __expf(S[mtl][r]);
                pv[mtl][r] = p;
                rs += p;
            }
#pragma unroll
            for (int off = 1; off < 16; off <<= 1) rs += __shfl_xor(rs, off);
            li[r] += rs;
        }
#pragma unroll
        for (int mtl = 0; mtl < 4; mtl++)
#pragma unroll
            for (int r = 0; r < 4; r++)
                sP[(quad * 4 + r) * 72 + mtl * 16 + col] = f2bf(pv[mtl][r]);
        __syncthreads();
        short8 pf[2];
#pragma unroll
        for (int ks = 0; ks < 2; ks++)
            pf[ks] = *(const short8*)&sP[col * 72 + ks * 32 + quad * 8];
#pragma unroll
        for (int ct = 0; ct < 8; ct++)
#pragma unroll
            for (int ks = 0; ks < 2; ks++) {
                short8 af = *(const short8*)&sG[(ct * 16 + col) * 72 + ks * 32 + quad * 8];
                oacc[ct] = __builtin_amdgcn_mfma_f32_16x16x32_bf16(af, pf[ks], oacc[ct], 0, 0, 0);
            }
    }
    __syncthreads();

    // ---------------- epilogue: normalize, O -> LDS, out-proj + bias + residual
    float inv;
    {
        float i0 = 1.0f / li[0], i1 = 1.0f / li[1], i2 = 1.0f / li[2], i3 = 1.0f / li[3];
        float b0 = __shfl(i0, bsrc), b1 = __shfl(i1, bsrc);
        float b2 = __shfl(i2, bsrc), b3 = __shfl(i3, bsrc);
        inv = (rsel == 0) ? b0 : (rsel == 1) ? b1 : (rsel == 2) ? b2 : b3;
    }
    {
        int q = wave * 16 + col;
#pragma unroll
        for (int ct = 0; ct < 8; ct++) {
            int ci = ct * 16 + quad * 4;
            uint2 v;
            unsigned short p0 = f2bf(oacc[ct][0] * inv);
            unsigned short p1 = f2bf(oacc[ct][1] * inv);
            unsigned short p2 = f2bf(oacc[ct][2] * inv);
            unsigned short p3 = f2bf(oacc[ct][3] * inv);
            v.x = (unsigned int)p0 | ((unsigned int)p1 << 16);
            v.y = (unsigned int)p2 | ((unsigned int)p3 << 16);
            *(uint2*)&sO[q * 136 + ci] = v;
        }
    }
    __syncthreads();

    for (int ot = 0; ot < 4; ot++) {
        {   // stage Wo tile [64 o][128 ci] bf16
            int rr = tid >> 2, seg = tid & 3;
            const float* wp = Wo + (size_t)(ot * 64 + rr) * NCI + seg * 32;
#pragma unroll
            for (int j = 0; j < 8; j++) {
                float4 v = *(const float4*)&wp[j * 4];
                ushort4 hv = { f2bf(v.x), f2bf(v.y), f2bf(v.z), f2bf(v.w) };
                *(ushort4*)&sWo[rr * 136 + seg * 32 + j * 4] = hv;
            }
        }
        __syncthreads();
        f32x4 acc[4];
#pragma unroll
        for (int j = 0; j < 4; j++)
#pragma unroll
            for (int e = 0; e < 4; e++) acc[j][e] = 0.f;
#pragma unroll
        for (int ks = 0; ks < 4; ks++) {
            short8 af = *(const short8*)&sWo[(wave * 16 + col) * 136 + ks * 32 + quad * 8];
#pragma unroll
            for (int j = 0; j < 4; j++) {
                short8 bf = *(const short8*)&sO[(j * 16 + col) * 136 + ks * 32 + quad * 8];
                acc[j] = __builtin_amdgcn_mfma_f32_16x16x32_bf16(af, bf, acc[j], 0, 0, 0);
            }
        }
#pragma unroll
        for (int j = 0; j < 4; j++) {
#pragma unroll
            for (int e = 0; e < 4; e++) {
                int o = ot * 64 + wave * 16 + quad * 4 + e;
                size_t idx = ((size_t)(b * NC + o)) * NN + n0 + j * 16 + col;
                y[idx] = acc[j][e] + bo[o] + x[idx];
            }
        }
        __syncthreads();
    }
}

// ---------------------------------------------------------------- launch
// ws: phiH (4 MB) + phiL (4 MB) + g (4 MB) = 12 MB. No d_out scratch (k_attn
// writes y while reading only ws + x -> no inter-block race). f32 in/out.
extern "C" void kernel_launch(void* const* d_in, const int* in_sizes, int n_in,
                              void* d_out, int out_size, void* d_ws, size_t ws_size,
                              hipStream_t stream) {
    float* y = (float*)d_out;

    bool sizes_ok = (n_in == 9) &&
        in_sizes[0] == NB * NC * NN && in_sizes[1] == NCI * NC && in_sizes[2] == NCI &&
        in_sizes[3] == NCI * NC && in_sizes[4] == NCI && in_sizes[5] == NCI * NC &&
        in_sizes[6] == NCI && in_sizes[7] == NC * NCI && in_sizes[8] == NC &&
        out_size == NB * NC * NN;
    if (!sizes_ok) {
        k_fill<<<(out_size + 255) / 256, 256, 0, stream>>>(y, 777.0f, out_size);
        return;
    }
    if (ws_size < (size_t)16 * 1024 * 1024) {
        k_fill<<<(out_size + 255) / 256, 256, 0, stream>>>(y, 555.0f, out_size);
        return;
    }

    const float* x  = (const float*)d_in[0];
    const float* tw = (const float*)d_in[1];
    const float* tb = (const float*)d_in[2];
    const float* pw = (const float*)d_in[3];
    const float* pb = (const float*)d_in[4];
    const float* gw = (const float*)d_in[5];
    const float* gb = (const float*)d_in[6];
    const float* ow = (const float*)d_in[7];
    const float* obias = (const float*)d_in[8];

    unsigned short* ws16 = (unsigned short*)d_ws;
    unsigned short* phiH = ws16;                 // [B][N][Ci] bf16 hi
    unsigned short* phiL = ws16 + 2097152;       // [B][N][Ci] bf16 lo
    unsigned short* g    = ws16 + 4194304;       // [B][Ci][N] bf16

    k_qkv2<<<dim3(NN / 128, NB), 256, 0, stream>>>(x, pw, pb, gw, gb, phiH, phiL, g);
    k_attn<<<dim3(256), 256, 0, stream>>>(x, tw, tb, phiH, phiL, g, ow, obias, y);
}